// Round 1
// baseline (2050.423 us; speedup 1.0000x reference)
//
#include <hip/hip_runtime.h>
#include <hip/hip_bf16.h>
#include <math.h>

// MixerBlock: token-mix YAT + linear + residual, channel-mix YAT + linear + residual.
// Round 0: correctness-first fp32 tiled GEMMs, bf16 intermediates, fused yat epilogues.
#define B_   64
#define P_   196
#define C_   768
#define TM_  384
#define CM_  3072
#define EPSY 0.1f

typedef unsigned short u16;

__device__ __forceinline__ float bf2f(u16 v) {
    unsigned int u = ((unsigned int)v) << 16;
    return __uint_as_float(u);
}
__device__ __forceinline__ u16 f2bf(float f) {
    unsigned int u = __float_as_uint(f);
    unsigned int rounding = 0x7FFFu + ((u >> 16) & 1u);
    return (u16)((u + rounding) >> 16);
}

// xn1[b*C + c] = sum_p x[b,p,c]^2   (coalesced over c)
__global__ __launch_bounds__(256) void k_colnorm_x(const float* __restrict__ x,
                                                   float* __restrict__ xn1) {
    int idx = blockIdx.x * 256 + threadIdx.x;
    if (idx >= B_ * C_) return;
    int b = idx / C_, c = idx % C_;
    const float* p = x + (size_t)b * P_ * C_ + c;
    float s = 0.f;
    for (int i = 0; i < P_; ++i) { float v = p[(size_t)i * C_]; s = fmaf(v, v, s); }
    xn1[idx] = s;
}

// out[r] = sum_k a[r*len + k]^2, one wave per row
__global__ __launch_bounds__(256) void k_rownorm(const float* __restrict__ a,
                                                 float* __restrict__ out,
                                                 int rows, int len) {
    int wave = (blockIdx.x * 256 + threadIdx.x) >> 6;
    int lane = threadIdx.x & 63;
    if (wave >= rows) return;
    const float* r = a + (size_t)wave * len;
    float s = 0.f;
    for (int i = lane; i < len; i += 64) { float v = r[i]; s = fmaf(v, v, s); }
    #pragma unroll
    for (int off = 32; off > 0; off >>= 1) s += __shfl_down(s, off, 64);
    if (lane == 0) out[wave] = s;
}

// k1: h1[b,c,t] = yat over P.  A[m=c][k=p] = x[b,p,c] (contig in m), B[n=t][k=p]=tw.
__global__ __launch_bounds__(256) void k1_token_yat(
    const float* __restrict__ x, const float* __restrict__ tw,
    const float* __restrict__ tb, const float* __restrict__ alpha,
    const float* __restrict__ xn1, const float* __restrict__ twn,
    u16* __restrict__ h1) {
    __shared__ float As[16][64];  // [k][m]
    __shared__ float Bs[16][64];  // [k][n]
    const int b  = blockIdx.z;
    const int m0 = blockIdx.x * 64;  // c
    const int n0 = blockIdx.y * 64;  // t
    const int tid = threadIdx.x;
    const int tx = tid & 15, ty = tid >> 4;
    float acc[4][4] = {};
    const float* xb = x + (size_t)b * (P_ * C_);
    const int a_k = tid >> 4;           // 0..15
    const int a_m = (tid & 15) * 4;     // 0..60
    const int b_n = tid >> 2;           // 0..63
    const int b_k = (tid & 3) * 4;      // 0..12

    for (int k0 = 0; k0 < P_; k0 += 16) {
        int kk = k0 + a_k;
        float4 av = make_float4(0.f, 0.f, 0.f, 0.f);
        if (kk < P_) av = *(const float4*)(xb + (size_t)kk * C_ + m0 + a_m);
        *(float4*)&As[a_k][a_m] = av;
        const float* bsrc = tw + (size_t)(n0 + b_n) * P_ + k0 + b_k;
        #pragma unroll
        for (int u = 0; u < 4; ++u) {
            int kb = k0 + b_k + u;
            Bs[b_k + u][b_n] = (kb < P_) ? bsrc[u] : 0.f;
        }
        __syncthreads();
        #pragma unroll
        for (int k = 0; k < 16; ++k) {
            float a[4], bb[4];
            *(float4*)a  = *(const float4*)&As[k][ty * 4];
            *(float4*)bb = *(const float4*)&Bs[k][tx * 4];
            #pragma unroll
            for (int i = 0; i < 4; ++i)
                #pragma unroll
                for (int j = 0; j < 4; ++j)
                    acc[i][j] = fmaf(a[i], bb[j], acc[i][j]);
        }
        __syncthreads();
    }
    float al = alpha[0];
    float sb = (float)TM_ / logf((float)TM_ + 1.0f);
    float scale = powf(sqrtf(sb), al);
    #pragma unroll
    for (int i = 0; i < 4; ++i) {
        int c = m0 + ty * 4 + i;
        float xn = xn1[b * C_ + c];
        u16* dst = h1 + ((size_t)(b * C_ + c)) * TM_ + n0 + tx * 4;
        ushort4 pack;
        u16 o[4];
        #pragma unroll
        for (int j = 0; j < 4; ++j) {
            int t = n0 + tx * 4 + j;
            float dnb  = acc[i][j];
            float dot  = dnb + tb[t];
            float dist = twn[t] + xn - 2.f * dnb;
            o[j] = f2bf(scale * dot * dot / (dist + EPSY));
        }
        pack.x = o[0]; pack.y = o[1]; pack.z = o[2]; pack.w = o[3];
        *(ushort4*)dst = pack;
    }
}

// k2: x1[b,p,c] = x[b,p,c] + sum_t h1[b,c,t]*w2[p,t] + b2[p]
__global__ __launch_bounds__(256) void k2_token_out(
    const u16* __restrict__ h1, const float* __restrict__ w2,
    const float* __restrict__ b2, const float* __restrict__ x,
    float* __restrict__ x1) {
    __shared__ float As[16][64];  // [k][m], m=c
    __shared__ float Bs[16][64];  // [k][n], n=p
    const int b  = blockIdx.z;
    const int m0 = blockIdx.x * 64;  // c
    const int n0 = blockIdx.y * 64;  // p
    const int tid = threadIdx.x;
    const int tx = tid & 15, ty = tid >> 4;
    float acc[4][4] = {};
    const int r  = tid >> 2;        // 0..63
    const int k4 = (tid & 3) * 4;

    const u16* Abase = h1 + ((size_t)b * C_ + m0) * TM_;
    for (int k0 = 0; k0 < TM_; k0 += 16) {
        {
            ushort4 v = *(const ushort4*)(Abase + (size_t)r * TM_ + k0 + k4);
            As[k4 + 0][r] = bf2f(v.x);
            As[k4 + 1][r] = bf2f(v.y);
            As[k4 + 2][r] = bf2f(v.z);
            As[k4 + 3][r] = bf2f(v.w);
        }
        {
            int n = n0 + r;
            if (n < P_) {
                float4 v = *(const float4*)(w2 + (size_t)n * TM_ + k0 + k4);
                Bs[k4 + 0][r] = v.x; Bs[k4 + 1][r] = v.y;
                Bs[k4 + 2][r] = v.z; Bs[k4 + 3][r] = v.w;
            } else {
                Bs[k4 + 0][r] = 0.f; Bs[k4 + 1][r] = 0.f;
                Bs[k4 + 2][r] = 0.f; Bs[k4 + 3][r] = 0.f;
            }
        }
        __syncthreads();
        #pragma unroll
        for (int k = 0; k < 16; ++k) {
            float a[4], bb[4];
            *(float4*)a  = *(const float4*)&As[k][tx * 4];  // m over tx (contig writes)
            *(float4*)bb = *(const float4*)&Bs[k][ty * 4];  // n over ty
            #pragma unroll
            for (int i = 0; i < 4; ++i)
                #pragma unroll
                for (int j = 0; j < 4; ++j)
                    acc[i][j] = fmaf(a[i], bb[j], acc[i][j]);
        }
        __syncthreads();
    }
    #pragma unroll
    for (int j = 0; j < 4; ++j) {
        int n = n0 + ty * 4 + j;
        if (n >= P_) continue;
        size_t rowoff = ((size_t)b * P_ + n) * C_ + m0 + tx * 4;
        float4 xv = *(const float4*)(x + rowoff);
        float bias = b2[n];
        float4 res;
        res.x = xv.x + acc[0][j] + bias;
        res.y = xv.y + acc[1][j] + bias;
        res.z = xv.z + acc[2][j] + bias;
        res.w = xv.w + acc[3][j] + bias;
        *(float4*)(x1 + rowoff) = res;
    }
}

// k3: h3[m, n] = yat over C.  m in B*P (x1 rows contiguous), n in C_MLP (cw rows).
__global__ __launch_bounds__(256) void k3_chan_yat(
    const float* __restrict__ x1, const float* __restrict__ cw,
    const float* __restrict__ cb, const float* __restrict__ alpha,
    const float* __restrict__ xn2, const float* __restrict__ cwn,
    u16* __restrict__ h3) {
    __shared__ float As[16][64];
    __shared__ float Bs[16][64];
    const int m0 = blockIdx.x * 64;
    const int n0 = blockIdx.y * 64;
    const int tid = threadIdx.x;
    const int tx = tid & 15, ty = tid >> 4;
    float acc[4][4] = {};
    const int r  = tid >> 2;
    const int k4 = (tid & 3) * 4;

    for (int k0 = 0; k0 < C_; k0 += 16) {
        {
            float4 v = *(const float4*)(x1 + (size_t)(m0 + r) * C_ + k0 + k4);
            As[k4 + 0][r] = v.x; As[k4 + 1][r] = v.y;
            As[k4 + 2][r] = v.z; As[k4 + 3][r] = v.w;
        }
        {
            float4 v = *(const float4*)(cw + (size_t)(n0 + r) * C_ + k0 + k4);
            Bs[k4 + 0][r] = v.x; Bs[k4 + 1][r] = v.y;
            Bs[k4 + 2][r] = v.z; Bs[k4 + 3][r] = v.w;
        }
        __syncthreads();
        #pragma unroll
        for (int k = 0; k < 16; ++k) {
            float a[4], bb[4];
            *(float4*)a  = *(const float4*)&As[k][ty * 4];  // m over ty
            *(float4*)bb = *(const float4*)&Bs[k][tx * 4];  // n over tx (contig writes)
            #pragma unroll
            for (int i = 0; i < 4; ++i)
                #pragma unroll
                for (int j = 0; j < 4; ++j)
                    acc[i][j] = fmaf(a[i], bb[j], acc[i][j]);
        }
        __syncthreads();
    }
    float al = alpha[0];
    float sb = (float)CM_ / logf((float)CM_ + 1.0f);
    float scale = powf(sqrtf(sb), al);
    #pragma unroll
    for (int i = 0; i < 4; ++i) {
        int m = m0 + ty * 4 + i;
        float xn = xn2[m];
        u16* dst = h3 + (size_t)m * CM_ + n0 + tx * 4;
        ushort4 pack;
        u16 o[4];
        #pragma unroll
        for (int j = 0; j < 4; ++j) {
            int n = n0 + tx * 4 + j;
            float dnb  = acc[i][j];
            float dot  = dnb + cb[n];
            float dist = cwn[n] + xn - 2.f * dnb;
            o[j] = f2bf(scale * dot * dot / (dist + EPSY));
        }
        pack.x = o[0]; pack.y = o[1]; pack.z = o[2]; pack.w = o[3];
        *(ushort4*)dst = pack;
    }
}

// k4: out[m, n] = x1[m, n] + sum_k h3[m,k]*w4[n,k] + b4[n]
__global__ __launch_bounds__(256) void k4_chan_out(
    const u16* __restrict__ h3, const float* __restrict__ w4,
    const float* __restrict__ b4, const float* __restrict__ x1,
    float* __restrict__ out) {
    __shared__ float As[16][64];
    __shared__ float Bs[16][64];
    const int m0 = blockIdx.x * 64;
    const int n0 = blockIdx.y * 64;
    const int tid = threadIdx.x;
    const int tx = tid & 15, ty = tid >> 4;
    float acc[4][4] = {};
    const int r  = tid >> 2;
    const int k4 = (tid & 3) * 4;

    for (int k0 = 0; k0 < CM_; k0 += 16) {
        {
            ushort4 v = *(const ushort4*)(h3 + (size_t)(m0 + r) * CM_ + k0 + k4);
            As[k4 + 0][r] = bf2f(v.x);
            As[k4 + 1][r] = bf2f(v.y);
            As[k4 + 2][r] = bf2f(v.z);
            As[k4 + 3][r] = bf2f(v.w);
        }
        {
            float4 v = *(const float4*)(w4 + (size_t)(n0 + r) * CM_ + k0 + k4);
            Bs[k4 + 0][r] = v.x; Bs[k4 + 1][r] = v.y;
            Bs[k4 + 2][r] = v.z; Bs[k4 + 3][r] = v.w;
        }
        __syncthreads();
        #pragma unroll
        for (int k = 0; k < 16; ++k) {
            float a[4], bb[4];
            *(float4*)a  = *(const float4*)&As[k][ty * 4];  // m over ty
            *(float4*)bb = *(const float4*)&Bs[k][tx * 4];  // n over tx (contig writes)
            #pragma unroll
            for (int i = 0; i < 4; ++i)
                #pragma unroll
                for (int j = 0; j < 4; ++j)
                    acc[i][j] = fmaf(a[i], bb[j], acc[i][j]);
        }
        __syncthreads();
    }
    #pragma unroll
    for (int i = 0; i < 4; ++i) {
        int m = m0 + ty * 4 + i;
        size_t rowoff = (size_t)m * C_ + n0 + tx * 4;
        float4 xv = *(const float4*)(x1 + rowoff);
        float4 res;
        res.x = xv.x + acc[i][0] + b4[n0 + tx * 4 + 0];
        res.y = xv.y + acc[i][1] + b4[n0 + tx * 4 + 1];
        res.z = xv.z + acc[i][2] + b4[n0 + tx * 4 + 2];
        res.w = xv.w + acc[i][3] + b4[n0 + tx * 4 + 3];
        *(float4*)(out + rowoff) = res;
    }
}

extern "C" void kernel_launch(void* const* d_in, const int* in_sizes, int n_in,
                              void* d_out, int out_size, void* d_ws, size_t ws_size,
                              hipStream_t stream) {
    const float* x  = (const float*)d_in[0];
    const float* tw = (const float*)d_in[1];
    const float* tb = (const float*)d_in[2];
    const float* ta = (const float*)d_in[3];
    const float* w2 = (const float*)d_in[4];
    const float* b2 = (const float*)d_in[5];
    const float* cw = (const float*)d_in[6];
    const float* cb = (const float*)d_in[7];
    const float* ca = (const float*)d_in[8];
    const float* w4 = (const float*)d_in[9];
    const float* b4 = (const float*)d_in[10];
    float* out = (float*)d_out;

    // Workspace layout (h1 and h3 overlap in time -> share region 0)
    char* ws = (char*)d_ws;
    u16*   h1  = (u16*)ws;                               // B*C*TM bf16 (37.7 MB)
    u16*   h3  = (u16*)ws;                               // B*P*CM bf16 (77.1 MB), after h1 dead
    size_t off = (size_t)B_ * P_ * CM_ * sizeof(u16);    // 77,070,336
    float* x1  = (float*)(ws + off);  off += (size_t)B_ * P_ * C_ * sizeof(float);
    float* xn1 = (float*)(ws + off);  off += (size_t)B_ * C_ * sizeof(float);
    float* xn2 = (float*)(ws + off);  off += (size_t)B_ * P_ * sizeof(float);
    float* twn = (float*)(ws + off);  off += (size_t)TM_ * sizeof(float);
    float* cwn = (float*)(ws + off);  off += (size_t)CM_ * sizeof(float);

    k_colnorm_x<<<(B_ * C_ + 255) / 256, 256, 0, stream>>>(x, xn1);
    k_rownorm<<<(TM_ + 3) / 4, 256, 0, stream>>>(tw, twn, TM_, P_);
    k_rownorm<<<(CM_ + 3) / 4, 256, 0, stream>>>(cw, cwn, CM_, C_);

    k1_token_yat<<<dim3(C_ / 64, TM_ / 64, B_), 256, 0, stream>>>(
        x, tw, tb, ta, xn1, twn, h1);
    k2_token_out<<<dim3(C_ / 64, (P_ + 63) / 64, B_), 256, 0, stream>>>(
        h1, w2, b2, x, x1);
    k_rownorm<<<(B_ * P_ + 3) / 4, 256, 0, stream>>>(x1, xn2, B_ * P_, C_);
    k3_chan_yat<<<dim3((B_ * P_) / 64, CM_ / 64), 256, 0, stream>>>(
        x1, cw, cb, ca, xn2, cwn, h3);
    k4_chan_out<<<dim3((B_ * P_) / 64, C_ / 64), 256, 0, stream>>>(
        h3, w4, b4, x1, out);
}

// Round 2
// 488.744 us; speedup vs baseline: 4.1953x; 4.1953x over previous
//
#include <hip/hip_runtime.h>
#include <hip/hip_bf16.h>
#include <math.h>

// MixerBlock on MI355X — R2: all 4 GEMMs as bf16 MFMA (16x16x32), m97 structure:
// 128x128 tiles, 4 waves x (4x4 16x16 subtiles), global_load_lds width=16,
// A*B^T with A and B both row-major over K. Fused yat / linear+residual epilogues.
#define B_   64
#define P_   196
#define PPAD 224      // P padded to multiple of 32 for K dim of token yat
#define C_   768
#define TM_  384
#define CM_  3072
#define EPSY 0.1f

typedef unsigned short u16;
typedef __attribute__((ext_vector_type(8))) short bf16x8;
typedef __attribute__((ext_vector_type(4))) float f32x4;

__device__ __forceinline__ float bf2f(u16 v) {
    return __uint_as_float(((unsigned int)v) << 16);
}
__device__ __forceinline__ u16 f2bf(float f) {
    unsigned int u = __float_as_uint(f);
    unsigned int rounding = 0x7FFFu + ((u >> 16) & 1u);
    return (u16)((u + rounding) >> 16);
}

__device__ __forceinline__ void gl_lds16(const u16* g, u16* l) {
    __builtin_amdgcn_global_load_lds(
        (const __attribute__((address_space(1))) unsigned int*)g,
        (__attribute__((address_space(3))) unsigned int*)l,
        16, 0, 0);
}

// ---------------- prep kernels ----------------

// transpose x[b,p,c] f32 -> xT[(b*C+c)][PPAD] bf16, zero-padded p in [196,224)
__global__ __launch_bounds__(256) void k_prep_xT(const float* __restrict__ x,
                                                 u16* __restrict__ xT) {
    __shared__ u16 tile[32][33];
    const int b = blockIdx.z, p0 = blockIdx.x * 32, c0 = blockIdx.y * 32;
    const int tx = threadIdx.x & 31, ty = threadIdx.x >> 5;   // ty 0..7
    const float* xb = x + (size_t)b * P_ * C_;
    #pragma unroll
    for (int r = 0; r < 4; ++r) {
        int p = p0 + ty + r * 8;
        float v = (p < P_) ? xb[(size_t)p * C_ + c0 + tx] : 0.f;
        tile[ty + r * 8][tx] = f2bf(v);       // tile[p_local][c_local]
    }
    __syncthreads();
    u16* dst = xT + ((size_t)b * C_ + c0) * PPAD + p0;
    #pragma unroll
    for (int r = 0; r < 4; ++r) {
        int cl = ty + r * 8;
        dst[(size_t)cl * PPAD + tx] = tile[tx][cl];
    }
}

// rows x inlen f32 -> rows x outlen bf16 (zero pad), plus row norm of bf16 values
__global__ __launch_bounds__(256) void k_prep_pad_norm(const float* __restrict__ in,
                                                       u16* __restrict__ outb,
                                                       float* __restrict__ norm,
                                                       int rows, int inlen, int outlen) {
    int wave = (blockIdx.x * 256 + threadIdx.x) >> 6;
    int lane = threadIdx.x & 63;
    if (wave >= rows) return;
    const float* src = in + (size_t)wave * inlen;
    u16* dst = outb + (size_t)wave * outlen;
    float s = 0.f;
    for (int i = lane; i < outlen; i += 64) {
        float v = (i < inlen) ? src[i] : 0.f;
        u16 h = f2bf(v);
        dst[i] = h;
        float vv = bf2f(h);
        s = fmaf(vv, vv, s);
    }
    #pragma unroll
    for (int off = 32; off > 0; off >>= 1) s += __shfl_down(s, off, 64);
    if (lane == 0) norm[wave] = s;
}

// norms of bf16 rows
__global__ __launch_bounds__(256) void k_rownorm_bf(const u16* __restrict__ a,
                                                    float* __restrict__ out,
                                                    int rows, int len) {
    int wave = (blockIdx.x * 256 + threadIdx.x) >> 6;
    int lane = threadIdx.x & 63;
    if (wave >= rows) return;
    const u16* r = a + (size_t)wave * len;
    float s = 0.f;
    for (int i = lane; i < len; i += 64) { float v = bf2f(r[i]); s = fmaf(v, v, s); }
    #pragma unroll
    for (int off = 32; off > 0; off >>= 1) s += __shfl_down(s, off, 64);
    if (lane == 0) out[wave] = s;
}

// w2 (196x384) -> w2b (256x384) bf16, rows >=196 zero
__global__ __launch_bounds__(256) void k_prep_w2pad(const float* __restrict__ w2,
                                                    u16* __restrict__ w2b) {
    int idx = blockIdx.x * 256 + threadIdx.x;     // < 256*384
    int row = idx / TM_;
    w2b[idx] = (row < P_) ? f2bf(w2[(size_t)row * TM_ + (idx % TM_)]) : (u16)0;
}

// plain f32 -> bf16 copy, 4 at a time
__global__ __launch_bounds__(256) void k_prep_bf4(const float* __restrict__ in,
                                                  u16* __restrict__ out, int n4) {
    int idx = blockIdx.x * 256 + threadIdx.x;
    if (idx >= n4) return;
    float4 v = ((const float4*)in)[idx];
    ushort4 o;
    o.x = f2bf(v.x); o.y = f2bf(v.y); o.z = f2bf(v.z); o.w = f2bf(v.w);
    ((ushort4*)out)[idx] = o;
}

// ---------------- MFMA GEMM, 128x128 tile, C = A * B^T ----------------
// MODE 0: yat epilogue -> bf16 Hout.  needs biasN, wn, xn, alpha, sb.
// MODE 1: v = acc + biasM[row] + resF[row][col]; bf16 Bout. (k2, per-z B/out/res)
// MODE 2: v = acc + biasN[col] + bf2f(resB[row][col]); f32 Fout. (k4)
template <int MODE>
__global__ __launch_bounds__(256) void gemm_mfma(
    const u16* __restrict__ A, const u16* __restrict__ Bmat, size_t strideBz,
    int lda, int ldb, int KK, int Mstore,
    const float* __restrict__ biasN, const float* __restrict__ biasM,
    const float* __restrict__ wn, const float* __restrict__ xn,
    const float* __restrict__ alpha, float sb,
    u16* __restrict__ Hout, int ldh,
    const float* __restrict__ resF, size_t strideRz,
    const u16* __restrict__ resB,
    float* __restrict__ Fout, u16* __restrict__ Bout, int ldo, size_t strideOz) {
    __shared__ u16 As[128 * 32];
    __shared__ u16 Bs[128 * 32];
    const int t = threadIdx.x;
    const int wid = t >> 6, lane = t & 63;
    const int quad = lane >> 4, l15 = lane & 15;
    const int m0 = blockIdx.x * 128, n0 = blockIdx.y * 128;
    const u16* Bz = Bmat + (size_t)blockIdx.z * strideBz;

    f32x4 acc[4][4];
    #pragma unroll
    for (int i = 0; i < 4; ++i)
        #pragma unroll
        for (int j = 0; j < 4; ++j) acc[i][j] = (f32x4){0.f, 0.f, 0.f, 0.f};

    const u16* Aw = As + (wid >> 1) * (64 * 32);
    const u16* Bw = Bs + (wid & 1) * (64 * 32);

    for (int k0 = 0; k0 < KK; k0 += 32) {
        #pragma unroll
        for (int q = 0; q < 2; ++q) {
            int g = q * 256 + t;
            int row = g >> 2, kc = (g & 3) * 8;
            gl_lds16(A  + (size_t)(m0 + row) * lda + k0 + kc, As + q * 2048 + wid * 512);
            gl_lds16(Bz + (size_t)(n0 + row) * ldb + k0 + kc, Bs + q * 2048 + wid * 512);
        }
        __syncthreads();
        bf16x8 af[4], bfr[4];
        #pragma unroll
        for (int i = 0; i < 4; ++i)
            af[i] = *(const bf16x8*)(Aw + ((i * 16 + l15) * 32 + quad * 8));
        #pragma unroll
        for (int j = 0; j < 4; ++j)
            bfr[j] = *(const bf16x8*)(Bw + ((j * 16 + l15) * 32 + quad * 8));
        #pragma unroll
        for (int i = 0; i < 4; ++i)
            #pragma unroll
            for (int j = 0; j < 4; ++j)
                acc[i][j] = __builtin_amdgcn_mfma_f32_16x16x32_bf16(af[i], bfr[j], acc[i][j], 0, 0, 0);
        __syncthreads();
    }

    // C/D layout (verified m89): col = lane&15, row = quad*4 + reg
    const int rbase = m0 + (wid >> 1) * 64;
    const int cbase = n0 + (wid & 1) * 64;

    if (MODE == 0) {
        float scale = powf(sqrtf(sb), alpha[0]);
        #pragma unroll
        for (int i = 0; i < 4; ++i) {
            #pragma unroll
            for (int j = 0; j < 4; ++j) {
                int col = cbase + j * 16 + l15;
                float bn = biasN[col], wnn = wn[col];
                #pragma unroll
                for (int reg = 0; reg < 4; ++reg) {
                    int row = rbase + i * 16 + quad * 4 + reg;
                    float dnb = acc[i][j][reg];
                    float dot = dnb + bn;
                    float dist = wnn + xn[row] - 2.f * dnb;
                    Hout[(size_t)row * ldh + col] = f2bf(scale * dot * dot / (dist + EPSY));
                }
            }
        }
    } else if (MODE == 1) {
        const float* rz = resF + (size_t)blockIdx.z * strideRz;
        u16* oz = Bout + (size_t)blockIdx.z * strideOz;
        #pragma unroll
        for (int i = 0; i < 4; ++i) {
            #pragma unroll
            for (int reg = 0; reg < 4; ++reg) {
                int row = rbase + i * 16 + quad * 4 + reg;
                if (row >= Mstore) continue;
                float bm = biasM[row];
                #pragma unroll
                for (int j = 0; j < 4; ++j) {
                    int col = cbase + j * 16 + l15;
                    float v = acc[i][j][reg] + bm + rz[(size_t)row * ldo + col];
                    oz[(size_t)row * ldo + col] = f2bf(v);
                }
            }
        }
    } else {  // MODE 2
        #pragma unroll
        for (int i = 0; i < 4; ++i) {
            #pragma unroll
            for (int j = 0; j < 4; ++j) {
                int col = cbase + j * 16 + l15;
                float bn = biasN[col];
                #pragma unroll
                for (int reg = 0; reg < 4; ++reg) {
                    int row = rbase + i * 16 + quad * 4 + reg;
                    float v = acc[i][j][reg] + bn + bf2f(resB[(size_t)row * ldo + col]);
                    Fout[(size_t)row * ldo + col] = v;
                }
            }
        }
    }
}

extern "C" void kernel_launch(void* const* d_in, const int* in_sizes, int n_in,
                              void* d_out, int out_size, void* d_ws, size_t ws_size,
                              hipStream_t stream) {
    const float* x  = (const float*)d_in[0];
    const float* tw = (const float*)d_in[1];
    const float* tb = (const float*)d_in[2];
    const float* ta = (const float*)d_in[3];
    const float* w2 = (const float*)d_in[4];
    const float* b2 = (const float*)d_in[5];
    const float* cw = (const float*)d_in[6];
    const float* cb = (const float*)d_in[7];
    const float* ca = (const float*)d_in[8];
    const float* w4 = (const float*)d_in[9];
    const float* b4 = (const float*)d_in[10];
    float* out = (float*)d_out;

    // ---- workspace layout (~101.5 MB, aliased) ----
    char* ws = (char*)d_ws;
    // region A: h1 (37.75 MB) then xT (22 MB) live during k1/k2; h3 (77 MB) overwrites at k3
    u16* h1 = (u16*)ws;                                    // B*C*TM
    u16* xT = (u16*)(ws + 37748736);                       // (B*C) x PPAD
    u16* h3 = (u16*)ws;                                    // (B*P) x CM
    size_t off = 77070336;
    u16* x1b = (u16*)(ws + off); off += (size_t)B_ * P_ * C_ * 2;   // 19,267,584
    u16* twb = (u16*)(ws + off); off += (size_t)TM_ * PPAD * 2;     // 172,032
    u16* w2b = (u16*)(ws + off); off += (size_t)256 * TM_ * 2;      // 196,608
    u16* cwb = (u16*)(ws + off); off += (size_t)CM_ * C_ * 2;       // 4,718,592
    u16* w4b = (u16*)(ws + off); off += (size_t)C_ * CM_ * 2;       // 4,718,592
    float* xn1 = (float*)(ws + off); off += (size_t)B_ * C_ * 4;    // 196,608
    float* xn2 = (float*)(ws + off); off += (size_t)B_ * P_ * 4;    // 50,176
    float* twn = (float*)(ws + off); off += (size_t)TM_ * 4;
    float* cwn = (float*)(ws + off); off += (size_t)CM_ * 4;

    const float SBT = (float)TM_ / logf((float)TM_ + 1.0f);
    const float SBC = (float)CM_ / logf((float)CM_ + 1.0f);

    // ---- prep ----
    k_prep_xT<<<dim3(PPAD / 32, C_ / 32, B_), 256, 0, stream>>>(x, xT);
    k_prep_pad_norm<<<(TM_ + 3) / 4, 256, 0, stream>>>(tw, twb, twn, TM_, P_, PPAD);
    k_prep_pad_norm<<<(CM_ + 3) / 4, 256, 0, stream>>>(cw, cwb, cwn, CM_, C_, C_);
    k_prep_w2pad<<<256 * TM_ / 256, 256, 0, stream>>>(w2, w2b);
    k_prep_bf4<<<(C_ * CM_ / 4 + 255) / 256, 256, 0, stream>>>(w4, w4b, C_ * CM_ / 4);
    k_rownorm_bf<<<(B_ * C_ + 3) / 4, 256, 0, stream>>>(xT, xn1, B_ * C_, PPAD);

    // ---- k1: h1[(b*C+c)][t] = yat(xT, twb) ; M=49152 N=384 K=224 ----
    gemm_mfma<0><<<dim3(B_ * C_ / 128, TM_ / 128, 1), 256, 0, stream>>>(
        xT, twb, 0, PPAD, PPAD, PPAD, B_ * C_,
        tb, nullptr, twn, xn1, ta, SBT,
        h1, TM_, nullptr, 0, nullptr, nullptr, nullptr, 0, 0);

    // ---- k2: x1b[b][p][c] = x + w2 . h1[b]^T + b2 ; M=196(pad256) N=768 K=384 ----
    gemm_mfma<1><<<dim3(2, C_ / 128, B_), 256, 0, stream>>>(
        w2b, h1, (size_t)C_ * TM_, TM_, TM_, TM_, P_,
        nullptr, b2, nullptr, nullptr, nullptr, 0.f,
        nullptr, 0, x, (size_t)P_ * C_, nullptr,
        nullptr, x1b, C_, (size_t)P_ * C_);

    k_rownorm_bf<<<(B_ * P_ + 3) / 4, 256, 0, stream>>>(x1b, xn2, B_ * P_, C_);

    // ---- k3: h3[m][n] = yat(x1b, cwb) ; M=12544 N=3072 K=768 ----
    gemm_mfma<0><<<dim3(B_ * P_ / 128, CM_ / 128, 1), 256, 0, stream>>>(
        x1b, cwb, 0, C_, C_, C_, B_ * P_,
        cb, nullptr, cwn, xn2, ca, SBC,
        h3, CM_, nullptr, 0, nullptr, nullptr, nullptr, 0, 0);

    // ---- k4: out[m][c] = x1b + h3 . w4^T + b4 ; M=12544 N=768 K=3072 ----
    gemm_mfma<2><<<dim3(B_ * P_ / 128, C_ / 128, 1), 256, 0, stream>>>(
        h3, w4b, 0, CM_, CM_, CM_, B_ * P_,
        b4, nullptr, nullptr, nullptr, nullptr, 0.f,
        nullptr, 0, nullptr, 0, x1b,
        out, nullptr, C_, 0);
}

// Round 3
// 469.533 us; speedup vs baseline: 4.3669x; 1.0409x over previous
//
#include <hip/hip_runtime.h>
#include <hip/hip_bf16.h>
#include <math.h>

// MixerBlock on MI355X — R3: bf16 MFMA GEMMs (m97 structure).
// k1/k2/k3 = 128x128 tile; k4 retiled to 128x64 (N=768 too narrow for 128-col
// tiles: grid 588->1176 blocks, occupancy 2.3->4.6 blocks/CU).
// xn2 fused into k2 epilogue (atomics); weight preps merged to one launch.
#define B_   64
#define P_   196
#define PPAD 224
#define C_   768
#define TM_  384
#define CM_  3072
#define EPSY 0.1f

typedef unsigned short u16;
typedef __attribute__((ext_vector_type(8))) short bf16x8;
typedef __attribute__((ext_vector_type(4))) float f32x4;

__device__ __forceinline__ float bf2f(u16 v) {
    return __uint_as_float(((unsigned int)v) << 16);
}
__device__ __forceinline__ u16 f2bf(float f) {
    unsigned int u = __float_as_uint(f);
    unsigned int rounding = 0x7FFFu + ((u >> 16) & 1u);
    return (u16)((u + rounding) >> 16);
}

__device__ __forceinline__ void gl_lds16(const u16* g, u16* l) {
    __builtin_amdgcn_global_load_lds(
        (const __attribute__((address_space(1))) unsigned int*)g,
        (__attribute__((address_space(3))) unsigned int*)l,
        16, 0, 0);
}

// ---------------- prep ----------------

// transpose x[b,p,c] f32 -> xT[(b*C+c)][PPAD] bf16, zero-padded p in [196,224)
__global__ __launch_bounds__(256) void k_prep_xT(const float* __restrict__ x,
                                                 u16* __restrict__ xT) {
    __shared__ u16 tile[32][33];
    const int b = blockIdx.z, p0 = blockIdx.x * 32, c0 = blockIdx.y * 32;
    const int tx = threadIdx.x & 31, ty = threadIdx.x >> 5;
    const float* xb = x + (size_t)b * P_ * C_;
    #pragma unroll
    for (int r = 0; r < 4; ++r) {
        int p = p0 + ty + r * 8;
        float v = (p < P_) ? xb[(size_t)p * C_ + c0 + tx] : 0.f;
        tile[ty + r * 8][tx] = f2bf(v);
    }
    __syncthreads();
    u16* dst = xT + ((size_t)b * C_ + c0) * PPAD + p0;
    #pragma unroll
    for (int r = 0; r < 4; ++r) {
        int cl = ty + r * 8;
        dst[(size_t)cl * PPAD + tx] = tile[tx][cl];
    }
}

__device__ __forceinline__ void pad_norm_body(const float* in, u16* outb, float* norm,
                                              int rows, int inlen, int outlen,
                                              int bid, int tid) {
    int wave = (bid * 256 + tid) >> 6;
    int lane = tid & 63;
    if (wave >= rows) return;
    const float* src = in + (size_t)wave * inlen;
    u16* dst = outb + (size_t)wave * outlen;
    float s = 0.f;
    for (int i = lane; i < outlen; i += 64) {
        float v = (i < inlen) ? src[i] : 0.f;
        u16 h = f2bf(v);
        dst[i] = h;
        float vv = bf2f(h);
        s = fmaf(vv, vv, s);
    }
    #pragma unroll
    for (int off = 32; off > 0; off >>= 1) s += __shfl_down(s, off, 64);
    if (lane == 0) norm[wave] = s;
}

// merged weight prep: tw pad+norm | cw pad+norm | w2 pad | w4 bf16
__global__ __launch_bounds__(256) void k_prep_weights(
    const float* __restrict__ tw, u16* __restrict__ twb, float* __restrict__ twn,
    const float* __restrict__ cw, u16* __restrict__ cwb, float* __restrict__ cwn,
    const float* __restrict__ w2, u16* __restrict__ w2b,
    const float* __restrict__ w4, u16* __restrict__ w4b) {
    int bid = blockIdx.x, tid = threadIdx.x;
    if (bid < 96) {
        pad_norm_body(tw, twb, twn, TM_, P_, PPAD, bid, tid);
    } else if (bid < 864) {
        pad_norm_body(cw, cwb, cwn, CM_, C_, C_, bid - 96, tid);
    } else if (bid < 1248) {
        int idx = (bid - 864) * 256 + tid;           // < 256*384
        int row = idx / TM_;
        w2b[idx] = (row < P_) ? f2bf(w2[(size_t)row * TM_ + (idx % TM_)]) : (u16)0;
    } else {
        int idx = (bid - 1248) * 256 + tid;          // < C_*CM_/4
        float4 v = ((const float4*)w4)[idx];
        ushort4 o;
        o.x = f2bf(v.x); o.y = f2bf(v.y); o.z = f2bf(v.z); o.w = f2bf(v.w);
        ((ushort4*)w4b)[idx] = o;
    }
}

// norms of bf16 rows (for xn1)
__global__ __launch_bounds__(256) void k_rownorm_bf(const u16* __restrict__ a,
                                                    float* __restrict__ out,
                                                    int rows, int len) {
    int wave = (blockIdx.x * 256 + threadIdx.x) >> 6;
    int lane = threadIdx.x & 63;
    if (wave >= rows) return;
    const u16* r = a + (size_t)wave * len;
    float s = 0.f;
    for (int i = lane; i < len; i += 64) { float v = bf2f(r[i]); s = fmaf(v, v, s); }
    #pragma unroll
    for (int off = 32; off > 0; off >>= 1) s += __shfl_down(s, off, 64);
    if (lane == 0) out[wave] = s;
}

// ---------------- MFMA GEMM 128x128, C = A * B^T ----------------
// MODE 0: yat epilogue -> bf16 Hout.
// MODE 1: v = acc + biasM[row] + resF; bf16 Bout; also atomics row-norms -> xn2out.
template <int MODE>
__global__ __launch_bounds__(256) void gemm_mfma(
    const u16* __restrict__ A, const u16* __restrict__ Bmat, size_t strideBz,
    int lda, int ldb, int KK, int Mstore,
    const float* __restrict__ biasN, const float* __restrict__ biasM,
    const float* __restrict__ wn, const float* __restrict__ xn,
    const float* __restrict__ alpha, float sb,
    u16* __restrict__ Hout, int ldh,
    const float* __restrict__ resF, size_t strideRz,
    float* __restrict__ xn2out,
    u16* __restrict__ Bout, int ldo, size_t strideOz) {
    __shared__ u16 As[128 * 32];
    __shared__ u16 Bs[128 * 32];
    const int t = threadIdx.x;
    const int wid = t >> 6, lane = t & 63;
    const int quad = lane >> 4, l15 = lane & 15;
    const int m0 = blockIdx.x * 128, n0 = blockIdx.y * 128;
    const u16* Bz = Bmat + (size_t)blockIdx.z * strideBz;

    f32x4 acc[4][4];
    #pragma unroll
    for (int i = 0; i < 4; ++i)
        #pragma unroll
        for (int j = 0; j < 4; ++j) acc[i][j] = (f32x4){0.f, 0.f, 0.f, 0.f};

    const u16* Aw = As + (wid >> 1) * (64 * 32);
    const u16* Bw = Bs + (wid & 1) * (64 * 32);

    for (int k0 = 0; k0 < KK; k0 += 32) {
        #pragma unroll
        for (int q = 0; q < 2; ++q) {
            int g = q * 256 + t;
            int row = g >> 2, kc = (g & 3) * 8;
            gl_lds16(A  + (size_t)(m0 + row) * lda + k0 + kc, As + q * 2048 + wid * 512);
            gl_lds16(Bz + (size_t)(n0 + row) * ldb + k0 + kc, Bs + q * 2048 + wid * 512);
        }
        __syncthreads();
        bf16x8 af[4], bfr[4];
        #pragma unroll
        for (int i = 0; i < 4; ++i)
            af[i] = *(const bf16x8*)(Aw + ((i * 16 + l15) * 32 + quad * 8));
        #pragma unroll
        for (int j = 0; j < 4; ++j)
            bfr[j] = *(const bf16x8*)(Bw + ((j * 16 + l15) * 32 + quad * 8));
        #pragma unroll
        for (int i = 0; i < 4; ++i)
            #pragma unroll
            for (int j = 0; j < 4; ++j)
                acc[i][j] = __builtin_amdgcn_mfma_f32_16x16x32_bf16(af[i], bfr[j], acc[i][j], 0, 0, 0);
        __syncthreads();
    }

    // C/D layout: col = lane&15, row = quad*4 + reg
    const int rbase = m0 + (wid >> 1) * 64;
    const int cbase = n0 + (wid & 1) * 64;

    if (MODE == 0) {
        float scale = powf(sqrtf(sb), alpha[0]);
        #pragma unroll
        for (int i = 0; i < 4; ++i) {
            #pragma unroll
            for (int j = 0; j < 4; ++j) {
                int col = cbase + j * 16 + l15;
                float bn = biasN[col], wnn = wn[col];
                #pragma unroll
                for (int reg = 0; reg < 4; ++reg) {
                    int row = rbase + i * 16 + quad * 4 + reg;
                    float dnb = acc[i][j][reg];
                    float dot = dnb + bn;
                    float dist = wnn + xn[row] - 2.f * dnb;
                    Hout[(size_t)row * ldh + col] = f2bf(scale * dot * dot / (dist + EPSY));
                }
            }
        }
    } else {  // MODE 1 (k2)
        const float* rz = resF + (size_t)blockIdx.z * strideRz;
        u16* oz = Bout + (size_t)blockIdx.z * strideOz;
        float* xrow = xn2out + (size_t)blockIdx.z * P_;
        #pragma unroll
        for (int i = 0; i < 4; ++i) {
            #pragma unroll
            for (int reg = 0; reg < 4; ++reg) {
                int row = rbase + i * 16 + quad * 4 + reg;
                if (row < Mstore) {
                    float bm = biasM[row];
                    float s = 0.f;
                    #pragma unroll
                    for (int j = 0; j < 4; ++j) {
                        int col = cbase + j * 16 + l15;
                        float v = acc[i][j][reg] + bm + rz[(size_t)row * ldo + col];
                        u16 h = f2bf(v);
                        oz[(size_t)row * ldo + col] = h;
                        float vb = bf2f(h);
                        s = fmaf(vb, vb, s);
                    }
                    // reduce over the 16 l15 lanes holding this row
                    s += __shfl_xor(s, 1, 64);
                    s += __shfl_xor(s, 2, 64);
                    s += __shfl_xor(s, 4, 64);
                    s += __shfl_xor(s, 8, 64);
                    if (l15 == 0) atomicAdd(&xrow[row], s);
                }
            }
        }
    }
}

// ---------------- k4: 128x64 tile, out = h3 . w4^T + b4 + res ----------------
__global__ __launch_bounds__(256) void gemm_k4(
    const u16* __restrict__ A, const u16* __restrict__ Bmat,
    const float* __restrict__ biasN, const u16* __restrict__ resB,
    float* __restrict__ Fout) {
    __shared__ u16 As[128 * 32];
    __shared__ u16 Bs[64 * 32];
    const int t = threadIdx.x;
    const int wid = t >> 6, lane = t & 63;
    const int quad = lane >> 4, l15 = lane & 15;
    const int m0 = blockIdx.x * 128, n0 = blockIdx.y * 64;

    f32x4 acc[4][2];
    #pragma unroll
    for (int i = 0; i < 4; ++i)
        #pragma unroll
        for (int j = 0; j < 2; ++j) acc[i][j] = (f32x4){0.f, 0.f, 0.f, 0.f};

    const u16* Aw = As + (wid >> 1) * (64 * 32);
    const u16* Bw = Bs + (wid & 1) * (32 * 32);
    const int arow = t >> 2, akc = (t & 3) * 8;

    for (int k0 = 0; k0 < CM_; k0 += 32) {
        gl_lds16(A + (size_t)(m0 + arow) * CM_ + k0 + akc,       As + wid * 512);
        gl_lds16(A + (size_t)(m0 + 64 + arow) * CM_ + k0 + akc,  As + 2048 + wid * 512);
        gl_lds16(Bmat + (size_t)(n0 + arow) * CM_ + k0 + akc,    Bs + wid * 512);
        __syncthreads();
        bf16x8 af[4], bfr[2];
        #pragma unroll
        for (int i = 0; i < 4; ++i)
            af[i] = *(const bf16x8*)(Aw + ((i * 16 + l15) * 32 + quad * 8));
        #pragma unroll
        for (int j = 0; j < 2; ++j)
            bfr[j] = *(const bf16x8*)(Bw + ((j * 16 + l15) * 32 + quad * 8));
        #pragma unroll
        for (int i = 0; i < 4; ++i)
            #pragma unroll
            for (int j = 0; j < 2; ++j)
                acc[i][j] = __builtin_amdgcn_mfma_f32_16x16x32_bf16(af[i], bfr[j], acc[i][j], 0, 0, 0);
        __syncthreads();
    }

    const int rbase = m0 + (wid >> 1) * 64;
    const int cbase = n0 + (wid & 1) * 32;
    #pragma unroll
    for (int i = 0; i < 4; ++i) {
        #pragma unroll
        for (int j = 0; j < 2; ++j) {
            int col = cbase + j * 16 + l15;
            float bn = biasN[col];
            #pragma unroll
            for (int reg = 0; reg < 4; ++reg) {
                int row = rbase + i * 16 + quad * 4 + reg;
                float v = acc[i][j][reg] + bn + bf2f(resB[(size_t)row * C_ + col]);
                Fout[(size_t)row * C_ + col] = v;
            }
        }
    }
}

extern "C" void kernel_launch(void* const* d_in, const int* in_sizes, int n_in,
                              void* d_out, int out_size, void* d_ws, size_t ws_size,
                              hipStream_t stream) {
    const float* x  = (const float*)d_in[0];
    const float* tw = (const float*)d_in[1];
    const float* tb = (const float*)d_in[2];
    const float* ta = (const float*)d_in[3];
    const float* w2 = (const float*)d_in[4];
    const float* b2 = (const float*)d_in[5];
    const float* cw = (const float*)d_in[6];
    const float* cb = (const float*)d_in[7];
    const float* ca = (const float*)d_in[8];
    const float* w4 = (const float*)d_in[9];
    const float* b4 = (const float*)d_in[10];
    float* out = (float*)d_out;

    // ---- workspace layout (~106.5 MB, aliased) ----
    char* ws = (char*)d_ws;
    u16* h1 = (u16*)ws;                                    // B*C*TM (37.7 MB)
    u16* xT = (u16*)(ws + 37748736);                       // (B*C) x PPAD (22 MB)
    u16* h3 = (u16*)ws;                                    // (B*P) x CM (77 MB), after k1/k2
    size_t off = 77070336;
    u16* x1b = (u16*)(ws + off); off += (size_t)B_ * P_ * C_ * 2;
    u16* twb = (u16*)(ws + off); off += (size_t)TM_ * PPAD * 2;
    u16* w2b = (u16*)(ws + off); off += (size_t)256 * TM_ * 2;
    u16* cwb = (u16*)(ws + off); off += (size_t)CM_ * C_ * 2;
    u16* w4b = (u16*)(ws + off); off += (size_t)C_ * CM_ * 2;
    float* xn1 = (float*)(ws + off); off += (size_t)B_ * C_ * 4;
    float* xn2 = (float*)(ws + off); off += (size_t)B_ * P_ * 4;
    float* twn = (float*)(ws + off); off += (size_t)TM_ * 4;
    float* cwn = (float*)(ws + off); off += (size_t)CM_ * 4;

    const float SBT = (float)TM_ / logf((float)TM_ + 1.0f);
    const float SBC = (float)CM_ / logf((float)CM_ + 1.0f);

    // ---- prep ----
    hipMemsetAsync(xn2, 0, (size_t)B_ * P_ * 4, stream);
    k_prep_weights<<<3552, 256, 0, stream>>>(tw, twb, twn, cw, cwb, cwn,
                                             w2, w2b, w4, w4b);
    k_prep_xT<<<dim3(PPAD / 32, C_ / 32, B_), 256, 0, stream>>>(x, xT);
    k_rownorm_bf<<<(B_ * C_ + 3) / 4, 256, 0, stream>>>(xT, xn1, B_ * C_, PPAD);

    // ---- k1: h1[(b*C+c)][t] = yat(xT, twb) ; M=49152 N=384 K=224 ----
    gemm_mfma<0><<<dim3(B_ * C_ / 128, TM_ / 128, 1), 256, 0, stream>>>(
        xT, twb, 0, PPAD, PPAD, PPAD, B_ * C_,
        tb, nullptr, twn, xn1, ta, SBT,
        h1, TM_, nullptr, 0, nullptr, nullptr, 0, 0);

    // ---- k2: x1b[b][p][c] = x + w2 . h1[b]^T + b2 ; fused xn2 ----
    gemm_mfma<1><<<dim3(2, C_ / 128, B_), 256, 0, stream>>>(
        w2b, h1, (size_t)C_ * TM_, TM_, TM_, TM_, P_,
        nullptr, b2, nullptr, nullptr, nullptr, 0.f,
        nullptr, 0, x, (size_t)P_ * C_, xn2,
        x1b, C_, (size_t)P_ * C_);

    // ---- k3: h3[m][n] = yat(x1b, cwb) ; M=12544 N=3072 K=768 ----
    gemm_mfma<0><<<dim3(B_ * P_ / 128, CM_ / 128, 1), 256, 0, stream>>>(
        x1b, cwb, 0, C_, C_, C_, B_ * P_,
        cb, nullptr, cwn, xn2, ca, SBC,
        h3, CM_, nullptr, 0, nullptr, nullptr, 0, 0);

    // ---- k4: out = x1b + h3 . w4^T + b4 ; 128x64 tiles, grid 98x12 ----
    gemm_k4<<<dim3(B_ * P_ / 128, C_ / 64), 256, 0, stream>>>(
        h3, w4b, b4, x1b, out);
}